// Round 1
// baseline (259.758 us; speedup 1.0000x reference)
//
#include <hip/hip_runtime.h>
#include <math.h>

#define NSPK 1024
#define NUTT 32
#define DIM  128
#define NROWS (NSPK * NUTT)
#define EPS 1e-8f

// ---------------------------------------------------------------------------
// K1a: per-speaker centroid. Block = one speaker, 128 threads (thread = dim d).
// Outputs: Sg[n][d] = sum_m e[n,m,d];  snorm2[n] = ||S||^2;
//          centT[d][n] = (S[d]/32) / max(||S||/32, eps)   (transposed+scaled)
// ---------------------------------------------------------------------------
__global__ __launch_bounds__(128) void k_cent(const float* __restrict__ emb,
                                              float* __restrict__ centT,
                                              float* __restrict__ Sg,
                                              float* __restrict__ snorm2) {
  int n = blockIdx.x;
  int d = threadIdx.x;
  const float* base = emb + (size_t)n * NUTT * DIM + d;
  float s = 0.f;
#pragma unroll
  for (int m = 0; m < NUTT; ++m) s += base[m * DIM];
  Sg[n * DIM + d] = s;

  float p = s * s;
#pragma unroll
  for (int mask = 1; mask < 64; mask <<= 1) p += __shfl_xor(p, mask, 64);
  __shared__ float red[2];
  if ((d & 63) == 0) red[d >> 6] = p;
  __syncthreads();
  float ss = red[0] + red[1];
  if (d == 0) snorm2[n] = ss;

  float cn = fmaxf(sqrtf(ss) * (1.0f / NUTT), EPS);  // ||cent|| = ||S||/32
  centT[d * NSPK + n] = s / (NUTT * cn);
}

// ---------------------------------------------------------------------------
// K1b: per-row stats. One wave per row (4 rows / 256-thread block).
//   e_n      = max(||e_r||, eps)
//   dot_own  = (dot(e,S) - ||e||^2)/31
//   ||excl||^2 = (||S||^2 - 2 dot(e,S) + ||e||^2)/31^2
//   ownl[r]  = w * dot_own/(e_n*ce_n) + b ;  rowscale[r] = w/e_n
// ---------------------------------------------------------------------------
__global__ __launch_bounds__(256) void k_rows(const float* __restrict__ emb,
                                              const float* __restrict__ Sg,
                                              const float* __restrict__ snorm2,
                                              const float* __restrict__ wp,
                                              const float* __restrict__ bp,
                                              float* __restrict__ rowscale,
                                              float* __restrict__ ownl) {
  int wid = threadIdx.x >> 6;
  int lane = threadIdx.x & 63;
  int r = blockIdx.x * 4 + wid;
  int n = r >> 5;  // r / NUTT

  float2 e2 = *(const float2*)(emb + (size_t)r * DIM + lane * 2);
  float2 s2 = *(const float2*)(Sg + (size_t)n * DIM + lane * 2);
  float pee = e2.x * e2.x + e2.y * e2.y;
  float pes = e2.x * s2.x + e2.y * s2.y;
#pragma unroll
  for (int mask = 1; mask < 64; mask <<= 1) {
    pee += __shfl_xor(pee, mask, 64);
    pes += __shfl_xor(pes, mask, 64);
  }
  if (lane == 0) {
    float ee = pee, es = pes, sn2 = snorm2[n];
    float en = fmaxf(sqrtf(ee), EPS);
    float dot_own = (es - ee) * (1.0f / (NUTT - 1));
    float ex2 = (sn2 - 2.0f * es + ee) * (1.0f / ((NUTT - 1) * (NUTT - 1)));
    float cen = fmaxf(sqrtf(ex2), EPS);
    float w = wp[0], b = bp[0];
    ownl[r] = w * dot_own / (en * cen) + b;
    rowscale[r] = w / en;
  }
}

// ---------------------------------------------------------------------------
// K2: fused GEMM + online logsumexp. One block per speaker (32 rows x 1024
// cols, 8 passes of 128 cols). LDS: A[d][m] 16KB, B[d][c] 64KB -> 2 blocks/CU.
// Thread tile 4 rows x 4 cols (outer product per d). Per-row LSE kept in
// registers, merged across the 32 col-group lanes by shuffle butterfly.
// ---------------------------------------------------------------------------
__global__ __launch_bounds__(256) void k_main(const float* __restrict__ emb,
                                              const float* __restrict__ centT,
                                              const float* __restrict__ rowscale,
                                              const float* __restrict__ ownl,
                                              const float* __restrict__ bp,
                                              float* __restrict__ out) {
  __shared__ __align__(16) float A[DIM * NUTT];   // [d][m]
  __shared__ __align__(16) float B[DIM * 128];    // [d][c]
  __shared__ float lred[8];

  int n = blockIdx.x;
  int t = threadIdx.x;

  // Stage A (transpose e rows of speaker n into [d][m]); conflict-free writes.
  {
    int m = t & 31;
    int d0 = t >> 5;
#pragma unroll
    for (int i = 0; i < 16; ++i) {
      int d = d0 + i * 8;
      A[d * NUTT + m] = emb[((size_t)n * NUTT + m) * DIM + d];
    }
  }

  int rg = t >> 5, cg = t & 31;
  int rb = rg * 4, cb = cg * 4;

  float bval = bp[0];
  float rs[4], ol[4];
#pragma unroll
  for (int i = 0; i < 4; ++i) {
    int row = n * NUTT + rb + i;
    rs[i] = rowscale[row];
    ol[i] = ownl[row];
  }

  float mrun[4], srun[4];
#pragma unroll
  for (int i = 0; i < 4; ++i) { mrun[i] = -INFINITY; srun[i] = 0.f; }

  for (int p = 0; p < 8; ++p) {
    int col_base = p * 128;
    __syncthreads();  // previous-pass B reads done (also covers A staging)
    // Stage B tile: coalesced float4 global reads, conflict-free b128 writes.
#pragma unroll
    for (int i = 0; i < 16; ++i) {
      int f4 = t + 256 * i;
      int d = f4 >> 5;
      int c4 = (f4 & 31) << 2;
      *(float4*)&B[d * 128 + c4] =
          *(const float4*)(centT + (size_t)d * NSPK + col_base + c4);
    }
    __syncthreads();

    float acc[4][4];
#pragma unroll
    for (int i = 0; i < 4; ++i)
#pragma unroll
      for (int j = 0; j < 4; ++j) acc[i][j] = 0.f;

#pragma unroll 8
    for (int d = 0; d < DIM; ++d) {
      float4 av = *(const float4*)&A[d * NUTT + rb];
      float4 bv = *(const float4*)&B[d * 128 + cb];
      float a_[4] = {av.x, av.y, av.z, av.w};
      float b_[4] = {bv.x, bv.y, bv.z, bv.w};
#pragma unroll
      for (int i = 0; i < 4; ++i)
#pragma unroll
        for (int j = 0; j < 4; ++j) acc[i][j] += a_[i] * b_[j];
    }

    // Epilogue: logits + online LSE merge for this pass.
#pragma unroll
    for (int i = 0; i < 4; ++i) {
      float l[4];
      float lmax = -INFINITY;
#pragma unroll
      for (int j = 0; j < 4; ++j) {
        int gc = col_base + cb + j;
        float lv = rs[i] * acc[i][j] + bval;
        if (gc == n) lv = ol[i];  // own-speaker column -> exclusive centroid
        l[j] = lv;
        lmax = fmaxf(lmax, lv);
      }
      float nm = fmaxf(mrun[i], lmax);
      float ssum = srun[i] * __expf(mrun[i] - nm);
#pragma unroll
      for (int j = 0; j < 4; ++j) ssum += __expf(l[j] - nm);
      mrun[i] = nm;
      srun[i] = ssum;
    }
  }

  // Merge (m,s) across the 32 lanes sharing this row group.
#pragma unroll
  for (int mask = 1; mask < 32; mask <<= 1) {
#pragma unroll
    for (int i = 0; i < 4; ++i) {
      float om = __shfl_xor(mrun[i], mask, 64);
      float os = __shfl_xor(srun[i], mask, 64);
      float nm = fmaxf(mrun[i], om);
      srun[i] = srun[i] * __expf(mrun[i] - nm) + os * __expf(om - nm);
      mrun[i] = nm;
    }
  }

  if (cg == 0) {
    float local = 0.f;
#pragma unroll
    for (int i = 0; i < 4; ++i) local += mrun[i] + logf(srun[i]) - ol[i];
    lred[rg] = local;
  }
  __syncthreads();
  if (t == 0) {
    float tot = 0.f;
#pragma unroll
    for (int i = 0; i < 8; ++i) tot += lred[i];
    atomicAdd(out, tot * (1.0f / NROWS));
  }
}

// ---------------------------------------------------------------------------
extern "C" void kernel_launch(void* const* d_in, const int* in_sizes, int n_in,
                              void* d_out, int out_size, void* d_ws, size_t ws_size,
                              hipStream_t stream) {
  const float* emb = (const float*)d_in[0];
  const float* wp  = (const float*)d_in[1];
  const float* bp  = (const float*)d_in[2];
  // d_in[3] = n_speakers, d_in[4] = n_utterances (fixed: 1024, 32)

  char* ws = (char*)d_ws;
  float* centT    = (float*)(ws);                          // 128*1024 f = 512 KB
  float* Sg       = (float*)(ws + 524288);                 // 1024*128 f = 512 KB
  float* snorm2   = (float*)(ws + 1048576);                // 1024 f
  float* rowscale = (float*)(ws + 1048576 + 4096);         // 32768 f
  float* ownl     = (float*)(ws + 1048576 + 4096 + 131072);// 32768 f
  float* out = (float*)d_out;

  hipMemsetAsync(d_out, 0, sizeof(float), stream);
  hipLaunchKernelGGL(k_cent, dim3(NSPK), dim3(128), 0, stream, emb, centT, Sg, snorm2);
  hipLaunchKernelGGL(k_rows, dim3(NROWS / 4), dim3(256), 0, stream,
                     emb, Sg, snorm2, wp, bp, rowscale, ownl);
  hipLaunchKernelGGL(k_main, dim3(NSPK), dim3(256), 0, stream,
                     emb, centT, rowscale, ownl, bp, out);
}

// Round 2
// 98.245 us; speedup vs baseline: 2.6440x; 2.6440x over previous
//
#include <hip/hip_runtime.h>
#include <math.h>

#define NSPK 1024
#define NUTT 32
#define DIM  128
#define NROWS (NSPK * NUTT)
#define EPS 1e-8f
#define LOG2E 1.44269504f

typedef __attribute__((ext_vector_type(8))) short short8;
typedef __attribute__((ext_vector_type(4))) float floatx4;

__device__ inline unsigned short f2bf(float f) {  // RNE fp32 -> bf16
  union { float f; unsigned u; } v; v.f = f;
  unsigned r = v.u + 0x7fffu + ((v.u >> 16) & 1u);
  return (unsigned short)(r >> 16);
}

// ---------------------------------------------------------------------------
// k_prep: block = 1 speaker, 256 threads.
//  - centN[n][d] = bf16 unit-normalized full centroid (row-major = MFMA B^T)
//  - per row r: rs2[r] = w*log2e/e_n ; olv[r] = own logit (fp32 exact);
//               eol[r] = exp(ol - M), M = b + |w| (fixed LSE max)
// ---------------------------------------------------------------------------
__global__ __launch_bounds__(256) void k_prep(const float* __restrict__ emb,
                                              const float* __restrict__ wp,
                                              const float* __restrict__ bp,
                                              unsigned short* __restrict__ centN,
                                              float* __restrict__ rs2,
                                              float* __restrict__ eol,
                                              float* __restrict__ olv) {
  __shared__ __align__(16) float E[32 * 132];  // padded stride 132
  __shared__ __align__(16) float Sl[128];
  __shared__ float red2[2];

  int n = blockIdx.x, t = threadIdx.x;

  // stage 32x128 fp32, coalesced float4
  const float4* e4 = (const float4*)emb + (size_t)n * 1024;
#pragma unroll
  for (int i = 0; i < 4; ++i) {
    int idx4 = t + 256 * i;
    int m = idx4 >> 5, d4 = (idx4 & 31) << 2;
    *(float4*)&E[m * 132 + d4] = e4[idx4];
  }
  __syncthreads();

  float s = 0.f;
  if (t < 128) {
    for (int m = 0; m < 32; ++m) s += E[m * 132 + t];
    Sl[t] = s;
    float p = s * s;
#pragma unroll
    for (int mask = 1; mask < 64; mask <<= 1) p += __shfl_xor(p, mask, 64);
    if ((t & 63) == 0) red2[t >> 6] = p;
  }
  __syncthreads();
  float ss = red2[0] + red2[1];  // ||S||^2

  if (t < 128) {
    float cn = fmaxf(sqrtf(ss) * (1.0f / NUTT), EPS);
    centN[(size_t)n * DIM + t] = f2bf(s / (NUTT * cn));
  }

  // per-row stats: 8 threads per row, 16 dims each
  int row = t >> 3, sub = t & 7;
  float ee = 0.f, es = 0.f;
  int base = row * 132 + sub * 16;
#pragma unroll
  for (int i = 0; i < 4; ++i) {
    float4 ev = *(const float4*)&E[base + i * 4];
    float4 sv = *(const float4*)&Sl[sub * 16 + i * 4];
    ee += ev.x * ev.x + ev.y * ev.y + ev.z * ev.z + ev.w * ev.w;
    es += ev.x * sv.x + ev.y * sv.y + ev.z * sv.z + ev.w * sv.w;
  }
#pragma unroll
  for (int mask = 1; mask < 8; mask <<= 1) {
    ee += __shfl_xor(ee, mask, 64);
    es += __shfl_xor(es, mask, 64);
  }
  if (sub == 0) {
    float w = wp[0], b = bp[0];
    float M = b + fabsf(w);
    float en = fmaxf(sqrtf(ee), EPS);
    float dot_own = (es - ee) * (1.0f / (NUTT - 1));
    float ex2 = (ss - 2.0f * es + ee) * (1.0f / ((NUTT - 1) * (NUTT - 1)));
    float cen = fmaxf(sqrtf(ex2), EPS);
    float ol = w * dot_own / (en * cen) + b;
    int r = n * NUTT + row;
    olv[r] = ol;
    eol[r] = exp2f((ol - M) * LOG2E);
    rs2[r] = w * LOG2E / en;
  }
}

// ---------------------------------------------------------------------------
// k_mfma: block = 2 speakers (64 rows) x all 1024 cols, 256 thr = 4 waves.
// Wave w: 64 rows x cols [w*256, w*256+256), 16 col-tiles of 16.
// A (64x128 bf16, LDS, pad 136) -> a-frags in regs; B read from global
// (centN row-major = B^T layout). Fixed-max LSE: s += exp2(rs2*acc + c2).
// ---------------------------------------------------------------------------
__global__ __launch_bounds__(256, 2) void k_mfma(const float* __restrict__ emb,
                                                 const unsigned short* __restrict__ centN,
                                                 const float* __restrict__ rs2g,
                                                 const float* __restrict__ eolg,
                                                 const float* __restrict__ olvg,
                                                 const float* __restrict__ wp,
                                                 const float* __restrict__ bp,
                                                 float* __restrict__ out) {
  __shared__ __align__(16) unsigned short A[64 * 136];
  __shared__ float sPart[4 * 64];

  int b = blockIdx.x, t = threadIdx.x;
  int wid = t >> 6, lane = t & 63;
  int lg = lane >> 4, lc = lane & 15;
  int s0 = b * 2;

  // stage A (64 rows x 128) fp32 -> bf16 LDS
  const float4* e4 = (const float4*)emb + (size_t)b * 2048;
#pragma unroll
  for (int i = 0; i < 8; ++i) {
    int idx4 = t + 256 * i;
    int lr = idx4 >> 5, d4 = (idx4 & 31) << 2;
    float4 v = e4[idx4];
    ushort4 bv;
    bv.x = f2bf(v.x); bv.y = f2bf(v.y); bv.z = f2bf(v.z); bv.w = f2bf(v.w);
    *(ushort4*)&A[lr * 136 + d4] = bv;
  }
  __syncthreads();

  // a-frags in registers: A[m=lc + rt*16][k = ks*32 + lg*8 + j]
  short8 af[4][4];
#pragma unroll
  for (int rt = 0; rt < 4; ++rt)
#pragma unroll
    for (int ks = 0; ks < 4; ++ks)
      af[rt][ks] = *(const short8*)&A[(rt * 16 + lc) * 136 + ks * 32 + lg * 8];

  // per-lane row constants (rows rt*16 + lg*4 + reg)
  float rsL[16], eolL[16];
#pragma unroll
  for (int rt = 0; rt < 4; ++rt) {
    float4 r4 = *(const float4*)&rs2g[b * 64 + rt * 16 + lg * 4];
    float4 o4 = *(const float4*)&eolg[b * 64 + rt * 16 + lg * 4];
    rsL[rt * 4 + 0] = r4.x; rsL[rt * 4 + 1] = r4.y; rsL[rt * 4 + 2] = r4.z; rsL[rt * 4 + 3] = r4.w;
    eolL[rt * 4 + 0] = o4.x; eolL[rt * 4 + 1] = o4.y; eolL[rt * 4 + 2] = o4.z; eolL[rt * 4 + 3] = o4.w;
  }

  float w = wp[0], bb = bp[0];
  float M = bb + fabsf(w);
  float c2 = (bb - M) * LOG2E;  // = -|w|*log2e

  float sAcc[16];
#pragma unroll
  for (int j = 0; j < 16; ++j) sAcc[j] = 0.f;

  int colbase = wid * 256;
#pragma unroll 2
  for (int ct = 0; ct < 16; ++ct) {
    int c0 = colbase + ct * 16;
    int col = c0 + lc;
    const short8* bptr = (const short8*)(centN + (size_t)col * DIM + lg * 8);
    short8 bf[4];
#pragma unroll
    for (int ks = 0; ks < 4; ++ks) bf[ks] = bptr[ks * 4];  // ks*32 elems

    floatx4 acc[4];
#pragma unroll
    for (int rt = 0; rt < 4; ++rt) acc[rt] = (floatx4){0.f, 0.f, 0.f, 0.f};
#pragma unroll
    for (int ks = 0; ks < 4; ++ks)
#pragma unroll
      for (int rt = 0; rt < 4; ++rt)
        acc[rt] = __builtin_amdgcn_mfma_f32_16x16x32_bf16(af[rt][ks], bf[ks], acc[rt], 0, 0, 0);

    bool fix = (unsigned)(s0 - c0) < 16u;  // own cols {s0,s0+1} in this tile
#pragma unroll
    for (int rt = 0; rt < 4; ++rt) {
      int own = s0 + (rt >> 1);
#pragma unroll
      for (int reg = 0; reg < 4; ++reg) {
        float l2 = fmaf(rsL[rt * 4 + reg], acc[rt][reg], c2);
        float e = exp2f(l2);
        if (fix && col == own) e = eolL[rt * 4 + reg];
        sAcc[rt * 4 + reg] += e;
      }
    }
  }

  // sum over the 16 col-lanes
#pragma unroll
  for (int mask = 1; mask < 16; mask <<= 1)
#pragma unroll
    for (int j = 0; j < 16; ++j) sAcc[j] += __shfl_xor(sAcc[j], mask, 64);

  if (lc == 0)
#pragma unroll
    for (int rt = 0; rt < 4; ++rt)
#pragma unroll
      for (int reg = 0; reg < 4; ++reg)
        sPart[wid * 64 + rt * 16 + lg * 4 + reg] = sAcc[rt * 4 + reg];
  __syncthreads();

  if (t < 64) {
    float st = sPart[t] + sPart[64 + t] + sPart[128 + t] + sPart[192 + t];
    float lossr = M + logf(st) - olvg[b * 64 + t];
#pragma unroll
    for (int mask = 1; mask < 64; mask <<= 1) lossr += __shfl_xor(lossr, mask, 64);
    if (t == 0) atomicAdd(out, lossr * (1.0f / NROWS));
  }
}

// ---------------------------------------------------------------------------
extern "C" void kernel_launch(void* const* d_in, const int* in_sizes, int n_in,
                              void* d_out, int out_size, void* d_ws, size_t ws_size,
                              hipStream_t stream) {
  const float* emb = (const float*)d_in[0];
  const float* wp  = (const float*)d_in[1];
  const float* bp  = (const float*)d_in[2];

  char* ws = (char*)d_ws;
  unsigned short* centN = (unsigned short*)ws;            // 256 KB
  float* rs2 = (float*)(ws + 262144);                     // 128 KB
  float* eol = (float*)(ws + 262144 + 131072);            // 128 KB
  float* olv = (float*)(ws + 262144 + 262144);            // 128 KB
  float* out = (float*)d_out;

  hipMemsetAsync(d_out, 0, sizeof(float), stream);
  hipLaunchKernelGGL(k_prep, dim3(NSPK), dim3(256), 0, stream,
                     emb, wp, bp, centN, rs2, eol, olv);
  hipLaunchKernelGGL(k_mfma, dim3(NSPK / 2), dim3(256), 0, stream,
                     emb, centN, rs2, eol, olv, wp, bp, out);
}

// Round 4
// 95.393 us; speedup vs baseline: 2.7230x; 1.0299x over previous
//
#include <hip/hip_runtime.h>
#include <hip/hip_cooperative_groups.h>
#include <math.h>

namespace cg = cooperative_groups;

#define NSPK 1024
#define NUTT 32
#define DIM  128
#define NROWS (NSPK * NUTT)
#define EPS 1e-8f
#define LOG2E 1.44269504f

typedef __attribute__((ext_vector_type(8))) short short8;
typedef __attribute__((ext_vector_type(4))) float floatx4;

__device__ inline unsigned short f2bf(float f) {  // RNE fp32 -> bf16
  union { float f; unsigned u; } v; v.f = f;
  unsigned r = v.u + 0x7fffu + ((v.u >> 16) & 1u);
  return (unsigned short)(r >> 16);
}

// ---------------------------------------------------------------------------
// Phase 1 (block b owns speakers {2b,2b+1} = rows [64b,64b+64)):
// column sums -> Sl; bf16 unit centroids -> centN (global); per-row stats ->
// LDS *and* global (global copies feed the non-coop fallback); bf16 A tile
// (pad 136) for MFMA. All emb reads straight from global (32KB/block, L1-hot).
// ---------------------------------------------------------------------------
__device__ __forceinline__ void phase1(
    int b, int t, const float* __restrict__ emb, float w, float bb, float M,
    unsigned short* __restrict__ centN, float* __restrict__ rs2g,
    float* __restrict__ eolg, float* __restrict__ olvg,
    float* Sl, float* red, float* rowRS, float* rowEOL, float* rowOLV,
    unsigned short* A) {
  int sp = t >> 7, d = t & 127;
  {
    const float* eb = emb + (size_t)(b * 2 + sp) * NUTT * DIM + d;
    float s = 0.f;
#pragma unroll
    for (int m = 0; m < NUTT; ++m) s += eb[m * DIM];
    Sl[sp * 128 + d] = s;
    float p = s * s;
#pragma unroll
    for (int mask = 1; mask < 64; mask <<= 1) p += __shfl_xor(p, mask, 64);
    if ((t & 63) == 0) red[t >> 6] = p;
  }
  __syncthreads();
  float ss0 = red[0] + red[1], ss1 = red[2] + red[3];

  {  // normalized bf16 centroid
    float ss = sp ? ss1 : ss0;
    float s = Sl[sp * 128 + d];
    float cn = fmaxf(sqrtf(ss) * (1.0f / NUTT), EPS);
    centN[(size_t)(b * 2 + sp) * DIM + d] = f2bf(s / (NUTT * cn));
  }

  {  // per-row stats: 4 threads/row, 32 dims each (coalesced, L1-hot)
    int row = t >> 2, sub = t & 3;
    int rsp = row >> 5;
    const float* er = emb + (size_t)(b * 64 + row) * DIM + sub * 32;
    const float* Srow = &Sl[rsp * 128 + sub * 32];
    float ee = 0.f, es = 0.f;
#pragma unroll
    for (int i = 0; i < 8; ++i) {
      float4 ev = *(const float4*)&er[i * 4];
      float4 sv = *(const float4*)&Srow[i * 4];
      ee += ev.x * ev.x + ev.y * ev.y + ev.z * ev.z + ev.w * ev.w;
      es += ev.x * sv.x + ev.y * sv.y + ev.z * sv.z + ev.w * sv.w;
    }
    ee += __shfl_xor(ee, 1, 64); es += __shfl_xor(es, 1, 64);
    ee += __shfl_xor(ee, 2, 64); es += __shfl_xor(es, 2, 64);
    if (sub == 0) {
      float ss = rsp ? ss1 : ss0;
      float en = fmaxf(sqrtf(ee), EPS);
      float dot_own = (es - ee) * (1.0f / (NUTT - 1));
      float ex2 = (ss - 2.f * es + ee) * (1.0f / ((NUTT - 1) * (NUTT - 1)));
      float cen = fmaxf(sqrtf(ex2), EPS);
      float ol = w * dot_own / (en * cen) + bb;
      float eo = exp2f((ol - M) * LOG2E);
      float rs = w * LOG2E / en;
      int gr = b * 64 + row;
      rowOLV[row] = ol; olvg[gr] = ol;
      rowEOL[row] = eo; eolg[gr] = eo;
      rowRS[row] = rs;  rs2g[gr] = rs;
    }
  }

  // bf16 A tile (64x128, pad 136) from global (L1-hot)
#pragma unroll
  for (int i = 0; i < 8; ++i) {
    int idx4 = t + 256 * i;
    int r = idx4 >> 5, d4 = (idx4 & 31) << 2;
    float4 v = *(const float4*)(emb + (size_t)b * 8192 + (size_t)idx4 * 4);
    ushort4 bv;
    bv.x = f2bf(v.x); bv.y = f2bf(v.y); bv.z = f2bf(v.z); bv.w = f2bf(v.w);
    *(ushort4*)&A[r * 136 + d4] = bv;
  }
}

// ---------------------------------------------------------------------------
// Phase 2: 64 rows x 1024 cols bf16 MFMA + fixed-max exp2 LSE.
// Returns block loss sum (valid on t==0 only).
// ---------------------------------------------------------------------------
__device__ __forceinline__ float phase2(
    int b, int t, const unsigned short* __restrict__ centN,
    const unsigned short* A, const float* rowRS, const float* rowEOL,
    const float* rowOLV, float M, float c2, float* sPart) {
  int wid = t >> 6, lane = t & 63, lg = lane >> 4, lc = lane & 15;
  int s0 = b * 2;

  short8 af[4][4];
#pragma unroll
  for (int rt = 0; rt < 4; ++rt)
#pragma unroll
    for (int ks = 0; ks < 4; ++ks)
      af[rt][ks] = *(const short8*)&A[(rt * 16 + lc) * 136 + ks * 32 + lg * 8];

  float rsL[16], eolL[16];
#pragma unroll
  for (int rt = 0; rt < 4; ++rt) {
    float4 r4 = *(const float4*)&rowRS[rt * 16 + lg * 4];
    float4 o4 = *(const float4*)&rowEOL[rt * 16 + lg * 4];
    rsL[rt * 4 + 0] = r4.x; rsL[rt * 4 + 1] = r4.y; rsL[rt * 4 + 2] = r4.z; rsL[rt * 4 + 3] = r4.w;
    eolL[rt * 4 + 0] = o4.x; eolL[rt * 4 + 1] = o4.y; eolL[rt * 4 + 2] = o4.z; eolL[rt * 4 + 3] = o4.w;
  }

  float sAcc[16];
#pragma unroll
  for (int j = 0; j < 16; ++j) sAcc[j] = 0.f;

  int colbase = wid * 256;
  int col0 = colbase + lc;
  const short8* cb8 = (const short8*)centN;

  short8 bcur[4], bnxt[4];
  {
    const short8* p = cb8 + (size_t)col0 * 16 + lg;
    bcur[0] = p[0]; bcur[1] = p[4]; bcur[2] = p[8]; bcur[3] = p[12];
  }

  for (int ct = 0; ct < 16; ++ct) {
    if (ct < 15) {
      const short8* p = cb8 + (size_t)(col0 + (ct + 1) * 16) * 16 + lg;
      bnxt[0] = p[0]; bnxt[1] = p[4]; bnxt[2] = p[8]; bnxt[3] = p[12];
    }
    floatx4 acc[4];
#pragma unroll
    for (int rt = 0; rt < 4; ++rt) acc[rt] = (floatx4){0.f, 0.f, 0.f, 0.f};
#pragma unroll
    for (int ks = 0; ks < 4; ++ks)
#pragma unroll
      for (int rt = 0; rt < 4; ++rt)
        acc[rt] = __builtin_amdgcn_mfma_f32_16x16x32_bf16(af[rt][ks], bcur[ks], acc[rt], 0, 0, 0);

    int c0 = colbase + ct * 16, col = c0 + lc;
    bool fix = (unsigned)(s0 - c0) < 16u;
#pragma unroll
    for (int rt = 0; rt < 4; ++rt) {
      int own = s0 + (rt >> 1);
#pragma unroll
      for (int reg = 0; reg < 4; ++reg) {
        float l2 = fmaf(rsL[rt * 4 + reg], acc[rt][reg], c2);
        float e = exp2f(l2);
        if (fix && col == own) e = eolL[rt * 4 + reg];
        sAcc[rt * 4 + reg] += e;
      }
    }
#pragma unroll
    for (int ks = 0; ks < 4; ++ks) bcur[ks] = bnxt[ks];
  }

#pragma unroll
  for (int mask = 1; mask < 16; mask <<= 1)
#pragma unroll
    for (int j = 0; j < 16; ++j) sAcc[j] += __shfl_xor(sAcc[j], mask, 64);

  if (lc == 0)
#pragma unroll
    for (int rt = 0; rt < 4; ++rt)
#pragma unroll
      for (int reg = 0; reg < 4; ++reg)
        sPart[wid * 64 + rt * 16 + lg * 4 + reg] = sAcc[rt * 4 + reg];
  __syncthreads();

  float blockSum = 0.f;
  if (t < 64) {
    float st = sPart[t] + sPart[64 + t] + sPart[128 + t] + sPart[192 + t];
    float lossr = M + logf(st) - rowOLV[t];
#pragma unroll
    for (int mask = 1; mask < 64; mask <<= 1) lossr += __shfl_xor(lossr, mask, 64);
    blockSum = lossr;
  }
  return blockSum;
}

// ---------------------------------------------------------------------------
// Cooperative single-dispatch kernel (512 blocks x 256). LDS ~21 KB.
// ---------------------------------------------------------------------------
__global__ __launch_bounds__(256, 2) void k_fused(const float* __restrict__ emb,
                                                  const float* __restrict__ wp,
                                                  const float* __restrict__ bp,
                                                  unsigned short* __restrict__ centN,
                                                  float* __restrict__ rs2g,
                                                  float* __restrict__ eolg,
                                                  float* __restrict__ olvg,
                                                  float* __restrict__ partial,
                                                  float* __restrict__ out) {
  __shared__ __align__(16) unsigned short A[64 * 136];
  __shared__ __align__(16) float Sl[2 * 128];
  __shared__ float red[4];
  __shared__ __align__(16) float rowRS[64], rowEOL[64], rowOLV[64];
  __shared__ __align__(16) float sPart[256];

  int b = blockIdx.x, t = threadIdx.x;
  float w = wp[0], bb = bp[0];
  float M = bb + fabsf(w);
  float c2 = -fabsf(w) * LOG2E;

  phase1(b, t, emb, w, bb, M, centN, rs2g, eolg, olvg,
         Sl, red, rowRS, rowEOL, rowOLV, A);

  __threadfence();
  cg::this_grid().sync();

  float v = phase2(b, t, centN, A, rowRS, rowEOL, rowOLV, M, c2, sPart);
  if (t == 0) partial[b] = v;

  __threadfence();
  cg::this_grid().sync();

  if (b == 0) {
    float s = partial[t] + partial[t + 256];
#pragma unroll
    for (int mask = 1; mask < 64; mask <<= 1) s += __shfl_xor(s, mask, 64);
    __syncthreads();
    if ((t & 63) == 0) red[t >> 6] = s;
    __syncthreads();
    if (t == 0) out[0] = (red[0] + red[1] + red[2] + red[3]) * (1.0f / NROWS);
  }
}

// ---------------------------------------------------------------------------
// Fallback path: two plain dispatches (proven round-2 structure, no memset).
// ---------------------------------------------------------------------------
__global__ __launch_bounds__(256) void k_prep_fb(const float* __restrict__ emb,
                                                 const float* __restrict__ wp,
                                                 const float* __restrict__ bp,
                                                 unsigned short* __restrict__ centN,
                                                 float* __restrict__ rs2g,
                                                 float* __restrict__ eolg,
                                                 float* __restrict__ olvg,
                                                 float* __restrict__ out) {
  __shared__ __align__(16) unsigned short A[64 * 136];
  __shared__ __align__(16) float Sl[2 * 128];
  __shared__ float red[4];
  __shared__ __align__(16) float rowRS[64], rowEOL[64], rowOLV[64];
  int b = blockIdx.x, t = threadIdx.x;
  float w = wp[0], bb = bp[0];
  float M = bb + fabsf(w);
  if (b == 0 && t == 0) out[0] = 0.f;  // zero before k_mfma_fb's atomics
  phase1(b, t, emb, w, bb, M, centN, rs2g, eolg, olvg,
         Sl, red, rowRS, rowEOL, rowOLV, A);
}

__global__ __launch_bounds__(256, 2) void k_mfma_fb(const float* __restrict__ emb,
                                                    const unsigned short* __restrict__ centN,
                                                    const float* __restrict__ rs2g,
                                                    const float* __restrict__ eolg,
                                                    const float* __restrict__ olvg,
                                                    const float* __restrict__ wp,
                                                    const float* __restrict__ bp,
                                                    float* __restrict__ out) {
  __shared__ __align__(16) unsigned short A[64 * 136];
  __shared__ __align__(16) float rowRS[64], rowEOL[64], rowOLV[64];
  __shared__ __align__(16) float sPart[256];

  int b = blockIdx.x, t = threadIdx.x;
  float w = wp[0], bb = bp[0];
  float M = bb + fabsf(w);
  float c2 = -fabsf(w) * LOG2E;

#pragma unroll
  for (int i = 0; i < 8; ++i) {
    int idx4 = t + 256 * i;
    int r = idx4 >> 5, d4 = (idx4 & 31) << 2;
    float4 v = *(const float4*)(emb + (size_t)b * 8192 + (size_t)idx4 * 4);
    ushort4 bv;
    bv.x = f2bf(v.x); bv.y = f2bf(v.y); bv.z = f2bf(v.z); bv.w = f2bf(v.w);
    *(ushort4*)&A[r * 136 + d4] = bv;
  }
  if (t < 64) {
    rowRS[t] = rs2g[b * 64 + t];
    rowEOL[t] = eolg[b * 64 + t];
    rowOLV[t] = olvg[b * 64 + t];
  }
  __syncthreads();

  float v = phase2(b, t, centN, A, rowRS, rowEOL, rowOLV, M, c2, sPart);
  if (t == 0) atomicAdd(out, v * (1.0f / NROWS));
}

// ---------------------------------------------------------------------------
// Load-time probe: validates cooperative launch under graph capture AND
// occupancy capacity for the real kernel. Runs in the .so constructor,
// outside kernel_launch, so hipMalloc/sync are allowed here.
// ---------------------------------------------------------------------------
static int g_use_coop = 0;

__global__ void k_coop_probe(int* flag) {
  cg::this_grid().sync();
  if (blockIdx.x == 0 && threadIdx.x == 0) flag[0] = 123;
}

namespace {
struct CoopInit {
  CoopInit() {
    int dev = 0;
    if (hipGetDevice(&dev) != hipSuccess) return;
    hipDeviceProp_t prop;
    if (hipGetDeviceProperties(&prop, dev) != hipSuccess) return;
    if (!prop.cooperativeLaunch) return;
    int maxb = 0;
    if (hipOccupancyMaxActiveBlocksPerMultiprocessor(&maxb, k_fused, 256, 0) != hipSuccess) return;
    if ((long long)maxb * prop.multiProcessorCount < 512) return;

    int* dflag = nullptr;
    if (hipMalloc(&dflag, sizeof(int)) != hipSuccess) return;
    hipMemset(dflag, 0, sizeof(int));
    hipStream_t s = nullptr;
    if (hipStreamCreate(&s) != hipSuccess) { hipFree(dflag); return; }

    bool ok = true;
    if (hipStreamBeginCapture(s, hipStreamCaptureModeRelaxed) != hipSuccess) ok = false;
    hipGraph_t g = nullptr;
    hipGraphExec_t ge = nullptr;
    if (ok) {
      void* args[] = {(void*)&dflag};
      if (hipLaunchCooperativeKernel((const void*)k_coop_probe, dim3(2), dim3(64),
                                     args, 0, s) != hipSuccess) ok = false;
      if (hipStreamEndCapture(s, &g) != hipSuccess || g == nullptr) ok = false;
      if (ok && hipGraphInstantiate(&ge, g, nullptr, nullptr, 0) != hipSuccess) ok = false;
      if (ok && hipGraphLaunch(ge, s) != hipSuccess) ok = false;
      if (hipStreamSynchronize(s) != hipSuccess) ok = false;
      if (ok) {
        int h = 0;
        hipMemcpy(&h, dflag, sizeof(int), hipMemcpyDeviceToHost);
        if (h != 123) ok = false;
      }
    }
    if (ge) hipGraphExecDestroy(ge);
    if (g) hipGraphDestroy(g);
    hipStreamDestroy(s);
    hipFree(dflag);
    g_use_coop = ok ? 1 : 0;
  }
};
static CoopInit g_init;
}  // namespace

// ---------------------------------------------------------------------------
extern "C" void kernel_launch(void* const* d_in, const int* in_sizes, int n_in,
                              void* d_out, int out_size, void* d_ws, size_t ws_size,
                              hipStream_t stream) {
  const float* emb = (const float*)d_in[0];
  const float* wp  = (const float*)d_in[1];
  const float* bp  = (const float*)d_in[2];

  char* ws = (char*)d_ws;
  unsigned short* centN = (unsigned short*)ws;        // 256 KB
  float* partial = (float*)(ws + 262144);             // 2 KB
  float* rs2g = (float*)(ws + 262144 + 4096);         // 128 KB
  float* eolg = (float*)(ws + 262144 + 4096 + 131072);
  float* olvg = (float*)(ws + 262144 + 4096 + 262144);
  float* out = (float*)d_out;

  if (g_use_coop) {
    void* args[] = {(void*)&emb, (void*)&wp, (void*)&bp, (void*)&centN,
                    (void*)&rs2g, (void*)&eolg, (void*)&olvg,
                    (void*)&partial, (void*)&out};
    hipLaunchCooperativeKernel((const void*)k_fused, dim3(512), dim3(256),
                               args, 0, stream);
  } else {
    hipLaunchKernelGGL(k_prep_fb, dim3(512), dim3(256), 0, stream,
                       emb, wp, bp, centN, rs2g, eolg, olvg, out);
    hipLaunchKernelGGL(k_mfma_fb, dim3(512), dim3(256), 0, stream,
                       emb, centN, rs2g, eolg, olvg, wp, bp, out);
  }
}